// Round 3
// baseline (359.323 us; speedup 1.0000x reference)
//
#include <hip/hip_runtime.h>

#define INSZ   2048
#define NH1    256
#define NH2    64
#define NB     8
#define BATCH  16384

#define TS     32                  // rows per wave-tile
#define NWORK  (BATCH / TS + NB)   // 520 work entries max

// W1f: [bkt][kb(64)][cg(16)][lane(64)][8] bf16  -> 524288 uint4 entries
#define W1F_U4   (NB * 64 * 16 * 64)        // 524288
#define W2F_U4   (NB * 8 * 4 * 64)          // 16384

// ws layout (bytes)
#define META_OFF  0                // 32 ints
#define WORK_OFF  1024             // 520 int2 = 4160 B
#define ORDER_OFF 8192             // 16384 ints = 65536 B
#define W1F_OFF   73728            // 8,388,608 B
#define W2F_OFF   (W1F_OFF + W1F_U4 * 16)   // 8,462,336
#define WS_NEED   (W2F_OFF + W2F_U4 * 16)   // 8,724,480
#define WS_NEED_SMALL (128 + BATCH * 4)

typedef float f4  __attribute__((ext_vector_type(4)));
typedef float f32x4 __attribute__((ext_vector_type(4)));
typedef short bf16x8 __attribute__((ext_vector_type(8)));

__device__ __forceinline__ unsigned short f2bf(float f) {
    unsigned u = __float_as_uint(f);
    u += 0x7fffu + ((u >> 16) & 1u);   // RNE
    return (unsigned short)(u >> 16);
}
__device__ __forceinline__ float clamp01(float v) { return fminf(fmaxf(v, 0.0f), 1.0f); }
__device__ __forceinline__ unsigned pack2(float a, float b) {
    return (unsigned)f2bf(a) | ((unsigned)f2bf(b) << 16);
}
__device__ __forceinline__ bf16x8 cvt8(f4 lo, f4 hi) {
    union { bf16x8 v; unsigned u[4]; } r;
    r.u[0] = pack2(lo[0], lo[1]); r.u[1] = pack2(lo[2], lo[3]);
    r.u[2] = pack2(hi[0], hi[1]); r.u[3] = pack2(hi[2], hi[3]);
    return r.v;
}

// ============================ pre-pass kernels ============================

__global__ void k_zero(int* meta) { if (threadIdx.x < 32) meta[threadIdx.x] = 0; }

__global__ void k_count(const int* __restrict__ idx, int* __restrict__ meta) {
    int t = blockIdx.x * 1024 + threadIdx.x;   // 4096 threads
    int local[NB];
#pragma unroll
    for (int b = 0; b < NB; b++) local[b] = 0;
    for (int i = t; i < BATCH; i += 4096) {
        int b = idx[i];
#pragma unroll
        for (int bb = 0; bb < NB; bb++) local[bb] += (b == bb) ? 1 : 0;
    }
#pragma unroll
    for (int bb = 0; bb < NB; bb++) {
        int v = local[bb];
        v += __shfl_xor(v, 1);  v += __shfl_xor(v, 2);  v += __shfl_xor(v, 4);
        v += __shfl_xor(v, 8);  v += __shfl_xor(v, 16); v += __shfl_xor(v, 32);
        if ((threadIdx.x & 63) == 0) atomicAdd(&meta[bb], v);
    }
}

__global__ void k_scan(int* __restrict__ meta, int2* __restrict__ work) {
    __shared__ int ts[NB + 1];
    int t = threadIdx.x;
    if (t == 0) {
        int run = 0, trun = 0;
        for (int b = 0; b < NB; b++) {
            int c = meta[b];
            meta[8 + b]  = run;
            meta[16 + b] = run;   // scatter cursor
            run += c;
            ts[b] = trun;
            trun += (c + TS - 1) / TS;
        }
        ts[NB] = trun;
    }
    __syncthreads();
    for (int i = t; i < NWORK; i += blockDim.x) {
        int b = -1;
#pragma unroll
        for (int bb = 0; bb < NB; bb++)
            if (i >= ts[bb] && i < ts[bb + 1]) b = bb;
        int2 v;
        if (b >= 0) { v.x = b; v.y = (i - ts[b]) * TS; }
        else        { v.x = -1; v.y = 0; }
        work[i] = v;
    }
}

__global__ void k_scatter(const int* __restrict__ idx, int* __restrict__ meta,
                          int* __restrict__ order) {
    __shared__ int wcnt[16][NB];
    __shared__ int sbase[NB];
    int t = threadIdx.x;
    int i = blockIdx.x * 1024 + t;
    int b = idx[i];
    int wv = t >> 6, lane = t & 63;
    unsigned long long mymask = 0;
#pragma unroll
    for (int bb = 0; bb < NB; bb++) {
        unsigned long long m = __ballot(b == bb);
        if (b == bb) mymask = m;
        if (lane == bb) wcnt[wv][bb] = (int)__popcll(m);
    }
    int myrank = (int)__popcll(mymask & ((1ull << lane) - 1ull));
    __syncthreads();
    if (t < NB) {
        int sum = 0;
        for (int w2 = 0; w2 < 16; w2++) { int c = wcnt[w2][t]; wcnt[w2][t] = sum; sum += c; }
        sbase[t] = atomicAdd(&meta[16 + t], sum);
    }
    __syncthreads();
    order[sbase[b] + wcnt[wv][b] + myrank] = i;
}

// pack W1/W2 into per-lane MFMA B-fragment order (bf16)
__global__ void k_pack3(const float* __restrict__ W1, const float* __restrict__ W2,
                        uint4* __restrict__ W1f, uint4* __restrict__ W2f) {
    int u = blockIdx.x * 256 + threadIdx.x;
    if (u < W1F_U4) {
        int lane = u & 63, cg = (u >> 6) & 15, kb = (u >> 10) & 63, bkt = u >> 16;
        int l15 = lane & 15, quad = lane >> 4;
        const float* p = W1 + (size_t)(bkt * NH1 + cg * 16 + l15) * INSZ + kb * 32 + quad * 8;
        f4 lo = *(const f4*)p, hi = *(const f4*)(p + 4);
        uint4 o;
        o.x = pack2(lo[0], lo[1]); o.y = pack2(lo[2], lo[3]);
        o.z = pack2(hi[0], hi[1]); o.w = pack2(hi[2], hi[3]);
        W1f[u] = o;
    } else {
        int v = u - W1F_U4;
        if (v >= W2F_U4) return;
        int lane = v & 63, cg2 = (v >> 6) & 3, kb2 = (v >> 8) & 7, bkt = v >> 11;
        int l15 = lane & 15, quad = lane >> 4;
        const float* p = W2 + (size_t)(bkt * NH2 + cg2 * 16 + l15) * NH1 + kb2 * 32 + quad * 8;
        f4 lo = *(const f4*)p, hi = *(const f4*)(p + 4);
        uint4 o;
        o.x = pack2(lo[0], lo[1]); o.y = pack2(lo[2], lo[3]);
        o.z = pack2(hi[0], hi[1]); o.w = pack2(hi[2], hi[3]);
        W2f[v] = o;
    }
}

// ============================ main: 1 wave = 32x256 tile, zero barriers ============================

__global__ __launch_bounds__(64, 1) void fused_v3(
    const float* __restrict__ x, const int* __restrict__ meta,
    const int2* __restrict__ work, const int* __restrict__ order,
    const short* __restrict__ W1f, const short* __restrict__ W2f,
    const float* __restrict__ b1, const float* __restrict__ b2,
    const float* __restrict__ W3, const float* __restrict__ b3,
    float* __restrict__ out)
{
    int2 wk = work[blockIdx.x];
    if (wk.x < 0) return;
    const int bkt = wk.x, base = wk.y;
    const int cnt = meta[bkt], off = meta[8 + bkt];

    __shared__ short sh1[TS * 264];    // 16.9 KB, per-wave h1 transpose buffer

    const int lane = threadIdx.x;
    const int l15 = lane & 15, quad = lane >> 4;

    int i0 = base + l15;      if (i0 > cnt - 1) i0 = cnt - 1;
    int i1 = base + 16 + l15; if (i1 > cnt - 1) i1 = cnt - 1;
    const float* xp0 = x + (size_t)order[off + i0] * INSZ + quad * 8;
    const float* xp1 = x + (size_t)order[off + i1] * INSZ + quad * 8;
    const short* wp  = W1f + ((size_t)bkt << 19) + lane * 8;

    f32x4 acc0[16], acc1[16];
#pragma unroll
    for (int cg = 0; cg < 16; cg++) { acc0[cg] = (f32x4)0.0f; acc1[cg] = (f32x4)0.0f; }

    bf16x8 b[16];
#pragma unroll
    for (int cg = 0; cg < 16; cg++) b[cg] = *(const bf16x8*)(wp + cg * 512);
    f4 a0lo = *(const f4*)xp0, a0hi = *(const f4*)(xp0 + 4);
    f4 a1lo = *(const f4*)xp1, a1hi = *(const f4*)(xp1 + 4);

#pragma unroll 1
    for (int kb = 0; kb < 64; kb++) {
        bf16x8 a0 = cvt8(a0lo, a0hi);
        bf16x8 a1 = cvt8(a1lo, a1hi);
        const int kn = (kb < 63) ? kb + 1 : kb;   // last iter: redundant reload, never OOB
        a0lo = *(const f4*)(xp0 + kn * 32); a0hi = *(const f4*)(xp0 + kn * 32 + 4);
        a1lo = *(const f4*)(xp1 + kn * 32); a1hi = *(const f4*)(xp1 + kn * 32 + 4);
#pragma unroll
        for (int cg = 0; cg < 16; cg++) {
            acc0[cg] = __builtin_amdgcn_mfma_f32_16x16x32_bf16(a0, b[cg], acc0[cg], 0, 0, 0);
            acc1[cg] = __builtin_amdgcn_mfma_f32_16x16x32_bf16(a1, b[cg], acc1[cg], 0, 0, 0);
            b[cg] = *(const bf16x8*)(wp + (size_t)(kn * 16 + cg) * 512);  // reload-in-place
        }
    }

    // layer-1 epilogue: bias + clip01 -> sh1 (bf16, row stride 264)
#pragma unroll
    for (int cg = 0; cg < 16; cg++) {
        float bias = b1[bkt * NH1 + cg * 16 + l15];
        int col = cg * 16 + l15;
#pragma unroll
        for (int r = 0; r < 4; r++) {
            sh1[(quad * 4 + r) * 264 + col]        = (short)f2bf(clamp01(acc0[cg][r] + bias));
            sh1[(16 + quad * 4 + r) * 264 + col]   = (short)f2bf(clamp01(acc1[cg][r] + bias));
        }
    }
    __syncthreads();   // single wave: just a waitcnt

    // layer 2: h2(32x64) = h1 @ W2_b^T, fragments straight from L2
    f32x4 c20[4], c21[4];
#pragma unroll
    for (int c = 0; c < 4; c++) { c20[c] = (f32x4)0.0f; c21[c] = (f32x4)0.0f; }
    const short* w2p = W2f + (size_t)bkt * 16384 + lane * 8;
#pragma unroll
    for (int kb2 = 0; kb2 < 8; kb2++) {
        bf16x8 a20 = *(const bf16x8*)&sh1[l15 * 264 + kb2 * 32 + quad * 8];
        bf16x8 a21 = *(const bf16x8*)&sh1[(16 + l15) * 264 + kb2 * 32 + quad * 8];
#pragma unroll
        for (int cg2 = 0; cg2 < 4; cg2++) {
            bf16x8 bw = *(const bf16x8*)(w2p + (kb2 * 4 + cg2) * 512);
            c20[cg2] = __builtin_amdgcn_mfma_f32_16x16x32_bf16(a20, bw, c20[cg2], 0, 0, 0);
            c21[cg2] = __builtin_amdgcn_mfma_f32_16x16x32_bf16(a21, bw, c21[cg2], 0, 0, 0);
        }
    }

    // layer-2 epilogue + layer-3 dot (in-lane over cg2, shuffle over l15)
    float s0[4] = {0, 0, 0, 0}, s1[4] = {0, 0, 0, 0};
#pragma unroll
    for (int cg2 = 0; cg2 < 4; cg2++) {
        float bias2 = b2[bkt * NH2 + cg2 * 16 + l15];
        float w3v   = W3[bkt * NH2 + cg2 * 16 + l15];
#pragma unroll
        for (int r = 0; r < 4; r++) {
            s0[r] += clamp01(c20[cg2][r] + bias2) * w3v;
            s1[r] += clamp01(c21[cg2][r] + bias2) * w3v;
        }
    }
    float b3v = b3[bkt];
#pragma unroll
    for (int r = 0; r < 4; r++) {
        float p0 = s0[r], p1 = s1[r];
        p0 += __shfl_xor(p0, 1); p0 += __shfl_xor(p0, 2);
        p0 += __shfl_xor(p0, 4); p0 += __shfl_xor(p0, 8);
        p1 += __shfl_xor(p1, 1); p1 += __shfl_xor(p1, 2);
        p1 += __shfl_xor(p1, 4); p1 += __shfl_xor(p1, 8);
        if (l15 == 0) {
            int row0 = quad * 4 + r;
            int row1 = 16 + quad * 4 + r;
            if (base + row0 < cnt) out[order[off + base + row0]] = p0 + b3v;
            if (base + row1 < cnt) out[order[off + base + row1]] = p1 + b3v;
        }
    }
}

// ============================ naive fallback ============================

__global__ void naive_mlp(const float* __restrict__ x, const int* __restrict__ idx,
                          const float* __restrict__ W1, const float* __restrict__ b1,
                          const float* __restrict__ W2, const float* __restrict__ b2,
                          const float* __restrict__ W3, const float* __restrict__ b3,
                          float* __restrict__ out)
{
    int i = blockIdx.x;
    int b = idx[i];
    __shared__ float sx[INSZ];
    __shared__ float sh1n[NH1];
    __shared__ float sh2n[NH2];
    for (int t = threadIdx.x; t < INSZ; t += 256) sx[t] = x[(size_t)i * INSZ + t];
    __syncthreads();
    int j = threadIdx.x;
    {
        const float* wr = W1 + (size_t)(b * NH1 + j) * INSZ;
        float acc = b1[b * NH1 + j];
        for (int k = 0; k < INSZ; k++) acc += sx[k] * wr[k];
        sh1n[j] = fminf(fmaxf(acc, 0.f), 1.f);
    }
    __syncthreads();
    if (j < NH2) {
        const float* wr = W2 + (size_t)(b * NH2 + j) * NH1;
        float acc = b2[b * NH2 + j];
        for (int k = 0; k < NH1; k++) acc += sh1n[k] * wr[k];
        sh2n[j] = fminf(fmaxf(acc, 0.f), 1.f);
    }
    __syncthreads();
    if (j == 0) {
        float acc = b3[b];
        for (int k = 0; k < NH2; k++) acc += sh2n[k] * W3[b * NH2 + k];
        out[i] = acc;
    }
}

extern "C" void kernel_launch(void* const* d_in, const int* in_sizes, int n_in,
                              void* d_out, int out_size, void* d_ws, size_t ws_size,
                              hipStream_t stream) {
    const float* x  = (const float*)d_in[0];
    const int* bidx = (const int*)d_in[1];
    const float* W1 = (const float*)d_in[2];
    const float* b1 = (const float*)d_in[3];
    const float* W2 = (const float*)d_in[4];
    const float* b2 = (const float*)d_in[5];
    const float* W3 = (const float*)d_in[6];
    const float* b3 = (const float*)d_in[7];
    float* out = (float*)d_out;

    if (ws_size >= (size_t)WS_NEED) {
        char* ws = (char*)d_ws;
        int*   meta  = (int*)(ws + META_OFF);
        int2*  work  = (int2*)(ws + WORK_OFF);
        int*   order = (int*)(ws + ORDER_OFF);
        uint4* W1f   = (uint4*)(ws + W1F_OFF);
        uint4* W2f   = (uint4*)(ws + W2F_OFF);

        k_zero<<<1, 64, 0, stream>>>(meta);
        k_count<<<4, 1024, 0, stream>>>(bidx, meta);
        k_scan<<<1, 512, 0, stream>>>(meta, work);
        k_scatter<<<BATCH / 1024, 1024, 0, stream>>>(bidx, meta, order);
        k_pack3<<<(W1F_U4 + W2F_U4) / 256, 256, 0, stream>>>(W1, W2, W1f, W2f);
        fused_v3<<<NWORK, 64, 0, stream>>>(x, meta, work, order,
                                           (const short*)W1f, (const short*)W2f,
                                           b1, b2, W3, b3, out);
    } else {
        naive_mlp<<<BATCH, 256, 0, stream>>>(x, bidx, W1, b1, W2, b2, W3, b3, out);
    }
}

// Round 4
// 276.699 us; speedup vs baseline: 1.2986x; 1.2986x over previous
//
#include <hip/hip_runtime.h>

#define INSZ   2048
#define NH1    256
#define NH2    64
#define NB     8
#define BATCH  16384

#define TS        64                 // rows per block-tile
#define MAXTILES  (BATCH / TS)       // 256 (worst case: all samples in one bucket)
#define GRIDX     (NB * MAXTILES)    // 2048, bkt = blockIdx % 8 -> XCD pin

// W1f: [bkt][kb(64)][cg(16)][lane(64)][8] bf16
#define W1F_U4   (NB * 64 * 16 * 64)        // 524288 uint4
#define W2F_U4   (NB * 8 * 4 * 64)          // 16384 uint4

// ws layout (bytes)
#define META_OFF  0                  // 32 ints: cnt[8], off[8], cursor[8]
#define ORDER_OFF 1024               // 16384 ints
#define W1F_OFF   (1024 + BATCH * 4)            // 66560
#define W2F_OFF   (W1F_OFF + W1F_U4 * 16)       // 8,455,168
#define WS_NEED   (W2F_OFF + W2F_U4 * 16)       // 8,717,312

typedef float f4  __attribute__((ext_vector_type(4)));
typedef float f32x4 __attribute__((ext_vector_type(4)));
typedef short bf16x8 __attribute__((ext_vector_type(8)));

__device__ __forceinline__ unsigned short f2bf(float f) {
    unsigned u = __float_as_uint(f);
    u += 0x7fffu + ((u >> 16) & 1u);   // RNE
    return (unsigned short)(u >> 16);
}
__device__ __forceinline__ float clamp01(float v) { return fminf(fmaxf(v, 0.0f), 1.0f); }
__device__ __forceinline__ unsigned pack2(float a, float b) {
    return (unsigned)f2bf(a) | ((unsigned)f2bf(b) << 16);
}

// async global -> LDS, 16 B per lane; LDS base wave-uniform
__device__ __forceinline__ void glds16(const short* gsrc, short* ldst) {
    __builtin_amdgcn_global_load_lds(
        (const __attribute__((address_space(1))) unsigned int*)gsrc,
        (__attribute__((address_space(3))) unsigned int*)ldst, 16, 0, 0);
}

// ============================ pre-pass kernels ============================

// count + serial scan in one single-block launch
__global__ void k_countscan(const int* __restrict__ idx, int* __restrict__ meta) {
    __shared__ int scnt[NB];
    int t = threadIdx.x;
    if (t < NB) scnt[t] = 0;
    __syncthreads();
    int local[NB];
#pragma unroll
    for (int bb = 0; bb < NB; bb++) local[bb] = 0;
    for (int i = t; i < BATCH; i += 1024) {
        int b = idx[i];
#pragma unroll
        for (int bb = 0; bb < NB; bb++) local[bb] += (b == bb) ? 1 : 0;
    }
#pragma unroll
    for (int bb = 0; bb < NB; bb++) {
        int v = local[bb];
        v += __shfl_xor(v, 1);  v += __shfl_xor(v, 2);  v += __shfl_xor(v, 4);
        v += __shfl_xor(v, 8);  v += __shfl_xor(v, 16); v += __shfl_xor(v, 32);
        if ((t & 63) == 0) atomicAdd(&scnt[bb], v);
    }
    __syncthreads();
    if (t == 0) {
        int run = 0;
        for (int b = 0; b < NB; b++) {
            int c = scnt[b];
            meta[b]      = c;
            meta[8 + b]  = run;
            meta[16 + b] = run;   // scatter cursor
            run += c;
        }
    }
}

__global__ void k_scatter(const int* __restrict__ idx, int* __restrict__ meta,
                          int* __restrict__ order) {
    __shared__ int wcnt[16][NB];
    __shared__ int sbase[NB];
    int t = threadIdx.x;
    int i = blockIdx.x * 1024 + t;
    int b = idx[i];
    int wv = t >> 6, lane = t & 63;
    unsigned long long mymask = 0;
#pragma unroll
    for (int bb = 0; bb < NB; bb++) {
        unsigned long long m = __ballot(b == bb);
        if (b == bb) mymask = m;
        if (lane == bb) wcnt[wv][bb] = (int)__popcll(m);
    }
    int myrank = (int)__popcll(mymask & ((1ull << lane) - 1ull));
    __syncthreads();
    if (t < NB) {
        int sum = 0;
        for (int w2 = 0; w2 < 16; w2++) { int c = wcnt[w2][t]; wcnt[w2][t] = sum; sum += c; }
        sbase[t] = atomicAdd(&meta[16 + t], sum);
    }
    __syncthreads();
    order[sbase[b] + wcnt[wv][b] + myrank] = i;
}

// pack W1/W2 into per-lane MFMA B-fragment order (bf16)
__global__ void k_pack(const float* __restrict__ W1, const float* __restrict__ W2,
                       uint4* __restrict__ W1f, uint4* __restrict__ W2f) {
    int u = blockIdx.x * 256 + threadIdx.x;
    if (u < W1F_U4) {
        int lane = u & 63, cg = (u >> 6) & 15, kb = (u >> 10) & 63, bkt = u >> 16;
        int l15 = lane & 15, quad = lane >> 4;
        const float* p = W1 + (size_t)(bkt * NH1 + cg * 16 + l15) * INSZ + kb * 32 + quad * 8;
        f4 lo = *(const f4*)p, hi = *(const f4*)(p + 4);
        uint4 o;
        o.x = pack2(lo[0], lo[1]); o.y = pack2(lo[2], lo[3]);
        o.z = pack2(hi[0], hi[1]); o.w = pack2(hi[2], hi[3]);
        W1f[u] = o;
    } else {
        int v = u - W1F_U4;
        if (v >= W2F_U4) return;
        int lane = v & 63, cg2 = (v >> 6) & 3, kb2 = (v >> 8) & 7, bkt = v >> 11;
        int l15 = lane & 15, quad = lane >> 4;
        const float* p = W2 + (size_t)(bkt * NH2 + cg2 * 16 + l15) * NH1 + kb2 * 32 + quad * 8;
        f4 lo = *(const f4*)p, hi = *(const f4*)(p + 4);
        uint4 o;
        o.x = pack2(lo[0], lo[1]); o.y = pack2(lo[2], lo[3]);
        o.z = pack2(hi[0], hi[1]); o.w = pack2(hi[2], hi[3]);
        W2f[v] = o;
    }
}

// ============================ main fused kernel ============================
// 64 rows x 256 cols per block, 4 waves; bkt = blockIdx%8 pins each bucket's
// weight stream to one XCD's L2. Fragment-order LDS image, glds dbuf, one
// barrier per K-step. Layers 2+3 wave-local (each wave owns its 16 rows).

__global__ __launch_bounds__(256, 2) void fused_v4(
    const float* __restrict__ x, const int* __restrict__ meta,
    const int* __restrict__ order,
    const short* __restrict__ W1f, const short* __restrict__ W2f,
    const float* __restrict__ b1, const float* __restrict__ b2,
    const float* __restrict__ W3, const float* __restrict__ b3,
    float* __restrict__ out)
{
    const int bkt  = blockIdx.x & 7;
    const int base = (blockIdx.x >> 3) * TS;
    const int cnt  = meta[bkt];
    if (cnt == 0 || base >= cnt) return;
    const int off = meta[8 + bkt];

    __shared__ short sW[2][8192];        // 2 x 16 KB W1 k-step image (fragment order)
    __shared__ short sX[2][2048];        // 2 x 4 KB  x k-step image (A-frag order)
    __shared__ short sh1[TS * 264];      // 33.8 KB h1 (bf16, row stride 264)

    const int t = threadIdx.x;
    const int lane = t & 63, w = t >> 6;
    const int l15 = lane & 15, quad = lane >> 4;

    // x staging assignment: thread t -> row xr = t>>2 (8 floats at (t&3)*8)
    const int xr = t >> 2, kq = t & 3;
    int ii = base + xr; if (ii > cnt - 1) ii = cnt - 1;
    const float* xrp = x + (size_t)order[off + ii] * INSZ + kq * 8;
    const int sxoff = (xr >> 4) * 512 + (kq * 16 + (xr & 15)) * 8;

    const short* wtile = W1f + (size_t)bkt * (64 * 8192);

    f32x4 acc[16];
#pragma unroll
    for (int cg = 0; cg < 16; cg++) acc[cg] = (f32x4)0.0f;

    // prologue: stage step 0, preload step-1 x into regs
    {
        const short* g = wtile;   // kb = 0
#pragma unroll
        for (int i = 0; i < 4; i++) {
            int cb = w * 4 + i;
            glds16(g + cb * 512 + lane * 8, &sW[0][cb * 512]);
        }
    }
    f4 xa = *(const f4*)xrp, xb = *(const f4*)(xrp + 4);
    {
        union { bf16x8 v; unsigned u[4]; } r;
        r.u[0] = pack2(xa[0], xa[1]); r.u[1] = pack2(xa[2], xa[3]);
        r.u[2] = pack2(xb[0], xb[1]); r.u[3] = pack2(xb[2], xb[3]);
        *(bf16x8*)&sX[0][sxoff] = r.v;
    }
    xa = *(const f4*)(xrp + 32); xb = *(const f4*)(xrp + 36);
    __syncthreads();

#pragma unroll 1
    for (int kb = 0; kb < 64; kb++) {
        const int p = kb & 1;
        if (kb < 63) {
            const short* g = wtile + (size_t)(kb + 1) * 8192;
#pragma unroll
            for (int i = 0; i < 4; i++) {
                int cb = w * 4 + i;
                glds16(g + cb * 512 + lane * 8, &sW[p ^ 1][cb * 512]);
            }
            union { bf16x8 v; unsigned u[4]; } r;
            r.u[0] = pack2(xa[0], xa[1]); r.u[1] = pack2(xa[2], xa[3]);
            r.u[2] = pack2(xb[0], xb[1]); r.u[3] = pack2(xb[2], xb[3]);
            *(bf16x8*)&sX[p ^ 1][sxoff] = r.v;
        }
        if (kb < 62) {
            xa = *(const f4*)(xrp + (kb + 2) * 32);
            xb = *(const f4*)(xrp + (kb + 2) * 32 + 4);
        }
        bf16x8 a = *(const bf16x8*)&sX[p][w * 512 + (quad * 16 + l15) * 8];
#pragma unroll
        for (int cg = 0; cg < 16; cg++) {
            bf16x8 bfr = *(const bf16x8*)&sW[p][(cg * 64 + lane) * 8];
            acc[cg] = __builtin_amdgcn_mfma_f32_16x16x32_bf16(a, bfr, acc[cg], 0, 0, 0);
        }
        __syncthreads();
    }

    // layer-1 epilogue: bias + clip01 -> sh1 rows w*16..w*16+15 (wave-local)
#pragma unroll
    for (int cg = 0; cg < 16; cg++) {
        int col = cg * 16 + l15;
        float bias = b1[bkt * NH1 + col];
#pragma unroll
        for (int r = 0; r < 4; r++) {
            int row = w * 16 + quad * 4 + r;
            sh1[row * 264 + col] = (short)f2bf(clamp01(acc[cg][r] + bias));
        }
    }
    // no barrier: wave w reads only the rows it wrote (compiler emits lgkmcnt)

    // layer 2: rows w*16..+15, all 64 cols, W2 fragments straight from L2
    f32x4 c2[4];
#pragma unroll
    for (int c = 0; c < 4; c++) c2[c] = (f32x4)0.0f;
    const short* w2p = W2f + (size_t)bkt * 16384 + lane * 8;
#pragma unroll
    for (int kb2 = 0; kb2 < 8; kb2++) {
        bf16x8 a2 = *(const bf16x8*)&sh1[(w * 16 + l15) * 264 + kb2 * 32 + quad * 8];
#pragma unroll
        for (int cg2 = 0; cg2 < 4; cg2++) {
            bf16x8 bw = *(const bf16x8*)(w2p + (kb2 * 4 + cg2) * 512);
            c2[cg2] = __builtin_amdgcn_mfma_f32_16x16x32_bf16(a2, bw, c2[cg2], 0, 0, 0);
        }
    }

    // layer-2 epilogue + layer-3 dot, fully wave-local
    float s[4] = {0, 0, 0, 0};
#pragma unroll
    for (int cg2 = 0; cg2 < 4; cg2++) {
        float bias2 = b2[bkt * NH2 + cg2 * 16 + l15];
        float w3v   = W3[bkt * NH2 + cg2 * 16 + l15];
#pragma unroll
        for (int r = 0; r < 4; r++)
            s[r] += clamp01(c2[cg2][r] + bias2) * w3v;
    }
    float b3v = b3[bkt];
#pragma unroll
    for (int r = 0; r < 4; r++) {
        float pp = s[r];
        pp += __shfl_xor(pp, 1); pp += __shfl_xor(pp, 2);
        pp += __shfl_xor(pp, 4); pp += __shfl_xor(pp, 8);
        if (l15 == 0) {
            int row = w * 16 + quad * 4 + r;
            if (base + row < cnt) out[order[off + base + row]] = pp + b3v;
        }
    }
}

// ============================ naive fallback ============================

__global__ void naive_mlp(const float* __restrict__ x, const int* __restrict__ idx,
                          const float* __restrict__ W1, const float* __restrict__ b1,
                          const float* __restrict__ W2, const float* __restrict__ b2,
                          const float* __restrict__ W3, const float* __restrict__ b3,
                          float* __restrict__ out)
{
    int i = blockIdx.x;
    int b = idx[i];
    __shared__ float sx[INSZ];
    __shared__ float sh1n[NH1];
    __shared__ float sh2n[NH2];
    for (int t = threadIdx.x; t < INSZ; t += 256) sx[t] = x[(size_t)i * INSZ + t];
    __syncthreads();
    int j = threadIdx.x;
    {
        const float* wr = W1 + (size_t)(b * NH1 + j) * INSZ;
        float acc = b1[b * NH1 + j];
        for (int k = 0; k < INSZ; k++) acc += sx[k] * wr[k];
        sh1n[j] = fminf(fmaxf(acc, 0.f), 1.f);
    }
    __syncthreads();
    if (j < NH2) {
        const float* wr = W2 + (size_t)(b * NH2 + j) * NH1;
        float acc = b2[b * NH2 + j];
        for (int k = 0; k < NH1; k++) acc += sh1n[k] * wr[k];
        sh2n[j] = fminf(fmaxf(acc, 0.f), 1.f);
    }
    __syncthreads();
    if (j == 0) {
        float acc = b3[b];
        for (int k = 0; k < NH2; k++) acc += sh2n[k] * W3[b * NH2 + k];
        out[i] = acc;
    }
}

extern "C" void kernel_launch(void* const* d_in, const int* in_sizes, int n_in,
                              void* d_out, int out_size, void* d_ws, size_t ws_size,
                              hipStream_t stream) {
    const float* x  = (const float*)d_in[0];
    const int* bidx = (const int*)d_in[1];
    const float* W1 = (const float*)d_in[2];
    const float* b1 = (const float*)d_in[3];
    const float* W2 = (const float*)d_in[4];
    const float* b2 = (const float*)d_in[5];
    const float* W3 = (const float*)d_in[6];
    const float* b3 = (const float*)d_in[7];
    float* out = (float*)d_out;

    if (ws_size >= (size_t)WS_NEED) {
        char* ws = (char*)d_ws;
        int*   meta  = (int*)(ws + META_OFF);
        int*   order = (int*)(ws + ORDER_OFF);
        uint4* W1f   = (uint4*)(ws + W1F_OFF);
        uint4* W2f   = (uint4*)(ws + W2F_OFF);

        k_countscan<<<1, 1024, 0, stream>>>(bidx, meta);
        k_scatter<<<BATCH / 1024, 1024, 0, stream>>>(bidx, meta, order);
        k_pack<<<(W1F_U4 + W2F_U4) / 256, 256, 0, stream>>>(W1, W2, W1f, W2f);
        fused_v4<<<GRIDX, 256, 0, stream>>>(x, meta, order,
                                            (const short*)W1f, (const short*)W2f,
                                            b1, b2, W3, b3, out);
    } else {
        naive_mlp<<<BATCH, 256, 0, stream>>>(x, bidx, W1, b1, W2, b2, W3, b3, out);
    }
}